// Round 22
// baseline (26.551 us; speedup 1.0000x reference)
//
#include <hip/hip_runtime.h>
#include <cstdint>
#include <cstddef>

typedef _Float16 half8 __attribute__((ext_vector_type(8)));
typedef float f32x4 __attribute__((ext_vector_type(4)));

static constexpr int kN  = 256;            // state dim (N == K)
static constexpr int kBM = 64;             // rows per block (4m x 2p waves)
static constexpr size_t kLDS = 72 * 1024;  // 72 nonzero chunks -> 2 blocks/CU (16 waves)

// Compact chunk base offsets: base[nt] = prefix sum of count[nt] = nt/2+1
__device__ __constant__ const int kBase[16] =
    {0, 1, 2, 4, 6, 9, 12, 16, 20, 25, 30, 36, 42, 49, 56, 64};
// Compact slot -> dense source chunk id ((ks>>2)*64 + nt*4 + (ks&3))
__device__ __constant__ const int kSrc[72] = {
    0, 4, 8, 9, 12, 13, 16, 17, 18, 20, 21, 22, 24, 25, 26, 27,
    28, 29, 30, 31, 32, 33, 34, 35, 96, 36, 37, 38, 39, 100, 40, 41,
    42, 43, 104, 105, 44, 45, 46, 47, 108, 109, 48, 49, 50, 51, 112, 113,
    114, 52, 53, 54, 55, 116, 117, 118, 56, 57, 58, 59, 120, 121, 122, 123,
    60, 61, 62, 63, 124, 125, 126, 127};

// Pack A_stacked[t] (fp32 [n][k]) into f16 frag order, ks-half outermost
// (dense 128-chunk layout; upper-triangle chunks are zeros, never DMA'd):
// a16[ ((ksh*16 + nt)*4 + ks2)*64 + l ] (half8 units)
//   = A[nt*16 + (l&15)][ (ksh*4 + ks2)*32 + (l>>4)*8 + j ]
__global__ __launch_bounds__(256) void hippo_prep(
    const float* __restrict__ A_stacked, const int* __restrict__ tptr,
    _Float16* __restrict__ a16)
{
    const int t = tptr[0];
    const float* __restrict__ A = A_stacked + (size_t)t * kN * kN;
    const int tid = blockIdx.x * 256 + threadIdx.x;   // 0..8191
    const int ksh = tid >> 12;
    const int nt  = (tid >> 8) & 15;
    const int ks2 = (tid >> 6) & 3;
    const int l   = tid & 63;
    const int row = nt * 16 + (l & 15);
    const int k0  = (ksh * 4 + ks2) * 32 + ((l >> 4) << 3);
    const float* __restrict__ src = A + (size_t)row * kN + k0;
    f32x4 v0 = *(const f32x4*)(src);
    f32x4 v1 = *(const f32x4*)(src + 4);
    half8 h;
    h[0] = (_Float16)v0[0]; h[1] = (_Float16)v0[1];
    h[2] = (_Float16)v0[2]; h[3] = (_Float16)v0[3];
    h[4] = (_Float16)v1[0]; h[5] = (_Float16)v1[1];
    h[6] = (_Float16)v1[2]; h[7] = (_Float16)v1[3];
    ((half8*)a16)[tid] = h;
}

// out[m][n] = sum_k c[m][k] * A_t[n][k] + b[n] * f[m]
// 512-thr blocks (8 waves = 4m x 2parity), 72 KiB compact triangular LDS
// -> 2 blocks/CU = 16 waves/CU = 4 waves/SIMD (2x all prior rounds).
// Wave (wm,wp): rows bid*64+wm*16, n-tiles {wp,wp+2,..,wp+14} (36 MFMA,
// parity-balanced). One barrier; phase A (ks4..7) under dv-flight; phase B
// nt-outer with streamed stores.
__global__ __launch_bounds__(512, 4) void hippo_gemm(
    const float* __restrict__ c, const float* __restrict__ f,
    const float* __restrict__ Bst, const int* __restrict__ tptr,
    const _Float16* __restrict__ a16, float* __restrict__ out)
{
    extern __shared__ char lds_raw[];

    const int tid  = threadIdx.x;
    const int l    = tid & 63;
    const int wid  = tid >> 6;          // 0..7
    const int wm   = wid & 3;           // m-tile (16 rows)
    const int wp   = wid >> 2;          // n-parity 0/1
    const int lo16 = l & 15;
    const int hi4  = l >> 4;
    const int bid  = blockIdx.x;
    const int m0   = bid * kBM + wm * 16;

    // ---- DMA all 72 compact chunks (wave wid stages slots wid+8i, i<9) ----
    const char* __restrict__ gsrc = (const char*)a16;
    #pragma unroll
    for (int i = 0; i < 9; ++i) {
        const int ci = i * 8 + wid;     // 0..71
        const size_t soff = (size_t)kSrc[ci] * 1024 + (size_t)l * 16;
        const size_t doff = (size_t)ci * 1024 + (size_t)l * 16;
        __builtin_amdgcn_global_load_lds(
            (const __attribute__((address_space(1))) void*)(gsrc + soff),
            (__attribute__((address_space(3))) void*)(lds_raw + doff),
            16, 0, 0);
    }

    // ---- c loads for ks 4..7 (phase A operands) ----
    const float* __restrict__ cptr = c + (size_t)(m0 + lo16) * kN + (hi4 << 3);
    f32x4 cv0[4], cv1[4];
    #pragma unroll
    for (int ks = 0; ks < 4; ++ks) {
        cv0[ks] = *(const f32x4*)(cptr + 128 + ks * 32);
        cv1[ks] = *(const f32x4*)(cptr + 128 + ks * 32 + 4);
    }

    // ---- bias loads (wave's 8 parity n-tiles) ----
    const int t = tptr[0];
    const float* __restrict__ brow = Bst + (size_t)t * kN;
    float bvs[8];
    #pragma unroll
    for (int j = 0; j < 8; ++j) bvs[j] = brow[(wp + 2 * j) * 16 + lo16];
    float fv[4];
    #pragma unroll
    for (int r = 0; r < 4; ++r) fv[r] = f[m0 + (hi4 << 2) + r];

    __syncthreads();   // THE ONLY BARRIER: LDS staged, cv/bias drained

    // ---- cvt af (cv dies) ----
    half8 af[4];
    #pragma unroll
    for (int ks = 0; ks < 4; ++ks) {
        af[ks][0] = (_Float16)cv0[ks][0]; af[ks][1] = (_Float16)cv0[ks][1];
        af[ks][2] = (_Float16)cv0[ks][2]; af[ks][3] = (_Float16)cv0[ks][3];
        af[ks][4] = (_Float16)cv1[ks][0]; af[ks][5] = (_Float16)cv1[ks][1];
        af[ks][6] = (_Float16)cv1[ks][2]; af[ks][7] = (_Float16)cv1[ks][3];
    }

    // ---- issue c loads for ks 0..3 (land under phase-A compute) ----
    f32x4 dv0[4], dv1[4];
    #pragma unroll
    for (int ks = 0; ks < 4; ++ks) {
        dv0[ks] = *(const f32x4*)(cptr + ks * 32);
        dv1[ks] = *(const f32x4*)(cptr + ks * 32 + 4);
    }

    // ---- phase A: ks 4..7, wave's parity tiles with nt >= 8+2*ks2 ----
    const half8* __restrict__ Bs = (const half8*)lds_raw;
    f32x4 acc[8];
    #pragma unroll
    for (int i = 0; i < 8; ++i) acc[i] = (f32x4){0.f, 0.f, 0.f, 0.f};
    #pragma unroll
    for (int ks2 = 0; ks2 < 4; ++ks2) {
        #pragma unroll
        for (int j = 0; j < 8; ++j) {
            const int nt = wp + 2 * j;
            if (nt >= 8 + 2 * ks2) {
                half8 bf = Bs[(kBase[nt] + 4 + ks2) * 64 + l];
                acc[j] = __builtin_amdgcn_mfma_f32_16x16x32_f16(af[ks2], bf, acc[j], 0, 0, 0);
            }
        }
    }

    // ---- cvt ag (waits dv per-use; dv dies) ----
    half8 ag[4];
    #pragma unroll
    for (int ks = 0; ks < 4; ++ks) {
        ag[ks][0] = (_Float16)dv0[ks][0]; ag[ks][1] = (_Float16)dv0[ks][1];
        ag[ks][2] = (_Float16)dv0[ks][2]; ag[ks][3] = (_Float16)dv0[ks][3];
        ag[ks][4] = (_Float16)dv1[ks][0]; ag[ks][5] = (_Float16)dv1[ks][1];
        ag[ks][6] = (_Float16)dv1[ks][2]; ag[ks][7] = (_Float16)dv1[ks][3];
    }

    // ---- phase B: nt-outer (parity tiles), ks 0..min(3,nt/2), streamed stores ----
    float* __restrict__ obase = out + (size_t)(m0 + (hi4 << 2)) * kN + lo16;
    #pragma unroll
    for (int j = 0; j < 8; ++j) {
        const int nt = wp + 2 * j;
        f32x4 a = acc[j];
        #pragma unroll
        for (int ks2 = 0; ks2 < 4; ++ks2) {
            if (ks2 <= (nt >> 1)) {
                half8 bf = Bs[(kBase[nt] + ks2) * 64 + l];
                a = __builtin_amdgcn_mfma_f32_16x16x32_f16(ag[ks2], bf, a, 0, 0, 0);
            }
        }
        #pragma unroll
        for (int r = 0; r < 4; ++r)
            obase[(size_t)r * kN + nt * 16] = a[r] + bvs[j] * fv[r];
    }
}

extern "C" void kernel_launch(void* const* d_in, const int* in_sizes, int n_in,
                              void* d_out, int out_size, void* d_ws, size_t ws_size,
                              hipStream_t stream) {
    const float* c   = (const float*)d_in[0];
    const float* f   = (const float*)d_in[1];
    const float* A   = (const float*)d_in[2];
    const float* B   = (const float*)d_in[3];
    const int*   t   = (const int*)d_in[4];
    float* out = (float*)d_out;
    _Float16* a16 = (_Float16*)d_ws;   // 128 KiB packed A[t] f16, ks-half-major

    const int batch = in_sizes[0] / kN;   // 32768

    hipFuncSetAttribute((const void*)hippo_gemm,
                        hipFuncAttributeMaxDynamicSharedMemorySize,
                        (int)kLDS);

    hipLaunchKernelGGL(hippo_prep, dim3(32), dim3(256), 0, stream, A, t, a16);
    hipLaunchKernelGGL(hippo_gemm, dim3(batch / kBM), dim3(512), kLDS, stream,
                       c, f, B, t, a16, out);
}

// Round 23
// 21.831 us; speedup vs baseline: 1.2162x; 1.2162x over previous
//
#include <hip/hip_runtime.h>
#include <cstdint>
#include <cstddef>

typedef _Float16 half8 __attribute__((ext_vector_type(8)));
typedef float f32x4 __attribute__((ext_vector_type(4)));

static constexpr int kN  = 256;            // state dim (N == K)
static constexpr int kBM = 64;             // rows per block (4 waves x 16)
static constexpr size_t kHalfB  = 64 * 1024;   // one ks-half of packed B
static constexpr size_t kLDS    = kHalfB;      // 64 KiB -> 2 blocks/CU

// Pack A_stacked[t] (fp32 [n][k]) into f16 frag order, ks-half outermost:
// a16[ ((ksh*16 + nt)*4 + ks2)*64 + l ] (half8 units)
//   = A[nt*16 + (l&15)][ (ksh*4 + ks2)*32 + (l>>4)*8 + j ]
__global__ __launch_bounds__(256) void hippo_prep(
    const float* __restrict__ A_stacked, const int* __restrict__ tptr,
    _Float16* __restrict__ a16)
{
    const int t = tptr[0];
    const float* __restrict__ A = A_stacked + (size_t)t * kN * kN;
    const int tid = blockIdx.x * 256 + threadIdx.x;   // 0..8191
    const int ksh = tid >> 12;
    const int nt  = (tid >> 8) & 15;
    const int ks2 = (tid >> 6) & 3;
    const int l   = tid & 63;
    const int row = nt * 16 + (l & 15);
    const int k0  = (ksh * 4 + ks2) * 32 + ((l >> 4) << 3);
    const float* __restrict__ src = A + (size_t)row * kN + k0;
    f32x4 v0 = *(const f32x4*)(src);
    f32x4 v1 = *(const f32x4*)(src + 4);
    half8 h;
    h[0] = (_Float16)v0[0]; h[1] = (_Float16)v0[1];
    h[2] = (_Float16)v0[2]; h[3] = (_Float16)v0[3];
    h[4] = (_Float16)v1[0]; h[5] = (_Float16)v1[1];
    h[6] = (_Float16)v1[2]; h[7] = (_Float16)v1[3];
    ((half8*)a16)[tid] = h;
}

// out[m][n] = sum_k c[m][k] * A_t[n][k] + b[n] * f[m]
// A_t is LOWER TRIANGULAR: frag (nt,ks) is zero unless nt >= 2*ks.
// R15 structure (4-wave blocks, 64 KiB ks-half LDS staging, 2 blocks/CU)
// with triangular skip: phase 1 = ks 4..7 (20/64 frags), phase 2 = ks 0..3
// (52/64 frags, nt-outer streamed stores). DMA/MFMA/LDS-reads drop 44%.
__global__ __launch_bounds__(256, 2) void hippo_gemm(
    const float* __restrict__ c, const float* __restrict__ f,
    const float* __restrict__ Bst, const int* __restrict__ tptr,
    const _Float16* __restrict__ a16, float* __restrict__ out)
{
    extern __shared__ char lds_raw[];

    const int tid  = threadIdx.x;
    const int l    = tid & 63;
    const int wid  = tid >> 6;          // 0..3
    const int lo16 = l & 15;
    const int hi4  = l >> 4;
    const int bid  = blockIdx.x;
    const int m0   = bid * kBM + wid * 16;

    // ---- DMA phase-1 half (ksh=1, ks 4..7): only chunks with nt >= 2*ks ----
    const char* __restrict__ gsrc1 = (const char*)a16 + kHalfB;   // ksh=1
    #pragma unroll
    for (int j = 0; j < 4; ++j) {
        const int nt = wid + j * 4;
        const int kmax = (nt - 8) >> 1;                // arithmetic shift ok
        for (int ks2 = 0; ks2 <= kmax && ks2 < 4; ++ks2) {
            const size_t off = (size_t)(nt * 4 + ks2) * 1024 + (size_t)l * 16;
            __builtin_amdgcn_global_load_lds(
                (const __attribute__((address_space(1))) void*)(gsrc1 + off),
                (__attribute__((address_space(3))) void*)(lds_raw + off),
                16, 0, 0);
        }
    }

    // ---- c loads for ks 4..7 ----
    const float* __restrict__ cptr = c + (size_t)(m0 + lo16) * kN + (hi4 << 3);
    f32x4 cv0[4], cv1[4];
    #pragma unroll
    for (int ks = 0; ks < 4; ++ks) {
        cv0[ks] = *(const f32x4*)(cptr + 128 + ks * 32);
        cv1[ks] = *(const f32x4*)(cptr + 128 + ks * 32 + 4);
    }

    // ---- bias loads ----
    const int t = tptr[0];
    const float* __restrict__ brow = Bst + (size_t)t * kN;
    float bvs[16];
    #pragma unroll
    for (int nt = 0; nt < 16; ++nt) bvs[nt] = brow[nt * 16 + lo16];
    float fv[4];
    #pragma unroll
    for (int r = 0; r < 4; ++r) fv[r] = f[m0 + (hi4 << 2) + r];

    __syncthreads();   // drains DMA(phase1) + c(ks4..7)

    // ---- cvt af (cv dies) ----
    half8 af[4];
    #pragma unroll
    for (int ks = 0; ks < 4; ++ks) {
        af[ks][0] = (_Float16)cv0[ks][0]; af[ks][1] = (_Float16)cv0[ks][1];
        af[ks][2] = (_Float16)cv0[ks][2]; af[ks][3] = (_Float16)cv0[ks][3];
        af[ks][4] = (_Float16)cv1[ks][0]; af[ks][5] = (_Float16)cv1[ks][1];
        af[ks][6] = (_Float16)cv1[ks][2]; af[ks][7] = (_Float16)cv1[ks][3];
    }

    // ---- HOISTED: issue c loads for ks 0..3 (hide under phase-1 compute) ----
    f32x4 dv0[4], dv1[4];
    #pragma unroll
    for (int ks = 0; ks < 4; ++ks) {
        dv0[ks] = *(const f32x4*)(cptr + ks * 32);
        dv1[ks] = *(const f32x4*)(cptr + ks * 32 + 4);
    }

    // ---- phase 1 compute: ks 4..7, only nt >= 8+2*ks2 (20 MFMA/wave) ----
    const half8* __restrict__ Bs = (const half8*)lds_raw;
    f32x4 acc[16];
    #pragma unroll
    for (int i = 0; i < 16; ++i) acc[i] = (f32x4){0.f, 0.f, 0.f, 0.f};
    #pragma unroll
    for (int ks2 = 0; ks2 < 4; ++ks2) {
        #pragma unroll
        for (int nt = 0; nt < 16; ++nt) {
            if (nt >= 8 + 2 * ks2) {
                half8 bf = Bs[(nt * 4 + ks2) * 64 + l];
                acc[nt] = __builtin_amdgcn_mfma_f32_16x16x32_f16(af[ks2], bf, acc[nt], 0, 0, 0);
            }
        }
    }

    __syncthreads();   // all LDS reads of phase-1 half done -> safe to overwrite

    // ---- DMA phase-2 half (ksh=0): only chunks with ks2 <= nt/2 (52) ----
    const char* __restrict__ gsrc0 = (const char*)a16;            // ksh=0
    #pragma unroll
    for (int j = 0; j < 4; ++j) {
        const int nt = wid + j * 4;
        const int kmax = nt >> 1;
        for (int ks2 = 0; ks2 <= kmax && ks2 < 4; ++ks2) {
            const size_t off = (size_t)(nt * 4 + ks2) * 1024 + (size_t)l * 16;
            __builtin_amdgcn_global_load_lds(
                (const __attribute__((address_space(1))) void*)(gsrc0 + off),
                (__attribute__((address_space(3))) void*)(lds_raw + off),
                16, 0, 0);
        }
    }
    half8 ag[4];
    #pragma unroll
    for (int ks = 0; ks < 4; ++ks) {
        ag[ks][0] = (_Float16)dv0[ks][0]; ag[ks][1] = (_Float16)dv0[ks][1];
        ag[ks][2] = (_Float16)dv0[ks][2]; ag[ks][3] = (_Float16)dv0[ks][3];
        ag[ks][4] = (_Float16)dv1[ks][0]; ag[ks][5] = (_Float16)dv1[ks][1];
        ag[ks][6] = (_Float16)dv1[ks][2]; ag[ks][7] = (_Float16)dv1[ks][3];
    }

    __syncthreads();   // drains DMA(phase2)

    // ---- phase 2: ks 0..3, nt-outer, only ks2 <= nt/2, streamed stores ----
    float* __restrict__ obase = out + (size_t)(m0 + (hi4 << 2)) * kN + lo16;
    #pragma unroll
    for (int nt = 0; nt < 16; ++nt) {
        f32x4 a = acc[nt];
        #pragma unroll
        for (int ks2 = 0; ks2 < 4; ++ks2) {
            if (ks2 <= (nt >> 1)) {
                half8 bf = Bs[(nt * 4 + ks2) * 64 + l];
                a = __builtin_amdgcn_mfma_f32_16x16x32_f16(ag[ks2], bf, a, 0, 0, 0);
            }
        }
        #pragma unroll
        for (int r = 0; r < 4; ++r)
            obase[(size_t)r * kN + nt * 16] = a[r] + bvs[nt] * fv[r];
    }
}

extern "C" void kernel_launch(void* const* d_in, const int* in_sizes, int n_in,
                              void* d_out, int out_size, void* d_ws, size_t ws_size,
                              hipStream_t stream) {
    const float* c   = (const float*)d_in[0];
    const float* f   = (const float*)d_in[1];
    const float* A   = (const float*)d_in[2];
    const float* B   = (const float*)d_in[3];
    const int*   t   = (const int*)d_in[4];
    float* out = (float*)d_out;
    _Float16* a16 = (_Float16*)d_ws;   // 128 KiB packed A[t] f16, ks-half-major

    const int batch = in_sizes[0] / kN;   // 32768

    hipFuncSetAttribute((const void*)hippo_gemm,
                        hipFuncAttributeMaxDynamicSharedMemorySize,
                        (int)kLDS);

    hipLaunchKernelGGL(hippo_prep, dim3(32), dim3(256), 0, stream, A, t, a16);
    hipLaunchKernelGGL(hippo_gemm, dim3(batch / kBM), dim3(256), kLDS, stream,
                       c, f, B, t, a16, out);
}